// Round 12
// baseline (101.978 us; speedup 1.0000x reference)
//
#include <hip/hip_runtime.h>
#include <hip/hip_bf16.h>
#include <stdint.h>

#define B_DIM 16384
#define H_DIM 512
#define KTOT  1024   // I + H
#define NP    2048   // 4 gates * H

typedef __attribute__((ext_vector_type(8))) short short8;
typedef __attribute__((ext_vector_type(4))) float floatx4;

static __device__ __forceinline__ unsigned short f2bf(float f) {
  unsigned int u = __float_as_uint(f);
  u += 0x7fffu + ((u >> 16) & 1u);
  return (unsigned short)(u >> 16);
}

static __device__ __forceinline__ short8 cvt8(floatx4 v0, floatx4 v1) {
  short8 o;
#pragma unroll
  for (int i = 0; i < 4; ++i) {
    o[i]     = (short)f2bf(v0[i]);
    o[i + 4] = (short)f2bf(v1[i]);
  }
  return o;
}

// ---------------------------------------------------------------------------
// Packed A (bf16), 16x16x32 frag-linear, BK=32 tiles (unchanged):
//   u = bm*32768 + kt*1024 + wr*512 + mh*256 + m4*64 + lane   (units of 8)
//   row = bm*256 + wr*128 + mh*64 + m4*16 + (lane&15)
//   k   = kt*32 + (lane>>4)*8 + j          (k<512 -> x, else z)
// Tile (bm,kt) = 8192 ushorts = 16KB = exact LDS A-tile image.
// ---------------------------------------------------------------------------
__global__ __launch_bounds__(256) void pack_a_kernel(
    const float* __restrict__ x, const float* __restrict__ z,
    unsigned short* __restrict__ Ap) {
  int u    = blockIdx.x * 256 + threadIdx.x;
  int lane = u & 63;
  int m4   = (u >> 6) & 3;
  int mh   = (u >> 8) & 1;
  int wr   = (u >> 9) & 1;
  int kt   = (u >> 10) & 31;
  int bm   = u >> 15;
  int row  = bm * 256 + wr * 128 + mh * 64 + m4 * 16 + (lane & 15);
  int k    = kt * 32 + ((lane >> 4) << 3);
  const float* src = (k < 512) ? (x + (uint64_t)row * 512 + k)
                               : (z + (uint64_t)row * 512 + (k - 512));
  floatx4 v0 = *reinterpret_cast<const floatx4*>(src);
  floatx4 v1 = *reinterpret_cast<const floatx4*>(src + 4);
  *reinterpret_cast<short8*>(Ap + (uint64_t)u * 8) = cvt8(v0, v1);
}

// ---------------------------------------------------------------------------
// Packed B (bf16), gate-major frags, BK=32 tiles (unchanged):
//   u = bn*16384 + kt*512 + wc*256 + g*64 + lane   (units of 8)
//   h = bn*32 + wc*16 + (lane&15); gate g; k = kt*32 + (lane>>4)*8 + j
// ---------------------------------------------------------------------------
__global__ __launch_bounds__(256) void pack_w_kernel(
    const float* __restrict__ Wi, const float* __restrict__ Wf,
    const float* __restrict__ Wc, const float* __restrict__ Wo,
    const float* __restrict__ Ui, const float* __restrict__ Uf,
    const float* __restrict__ Uc, const float* __restrict__ Uo,
    unsigned short* __restrict__ Bp) {
  int u    = blockIdx.x * 256 + threadIdx.x;
  int lane = u & 63;
  int g    = (u >> 6) & 3;
  int wc   = (u >> 8) & 1;
  int kt   = (u >> 9) & 31;
  int bn   = u >> 14;
  int h    = bn * 32 + wc * 16 + (lane & 15);
  int k    = kt * 32 + ((lane >> 4) << 3);
  const float* src;
  if (k < 512) {
    const float* W = (g == 0) ? Wi : (g == 1) ? Wf : (g == 2) ? Wc : Wo;
    src = W + (uint64_t)h * 512 + k;
  } else {
    const float* U = (g == 0) ? Ui : (g == 1) ? Uf : (g == 2) ? Uc : Uo;
    src = U + (uint64_t)h * 512 + (k - 512);
  }
  floatx4 v0 = *reinterpret_cast<const floatx4*>(src);
  floatx4 v1 = *reinterpret_cast<const floatx4*>(src + 4);
  *reinterpret_cast<short8*>(Bp + (uint64_t)u * 8) = cvt8(v0, v1);
}

// stage A-tile (16KB): 256 thr x 16B x 4 instrs
static __device__ __forceinline__ void stageA(const unsigned short* g,
                                              unsigned short* l, int tid) {
#pragma unroll
  for (int r = 0; r < 4; ++r)
    __builtin_amdgcn_global_load_lds(
        (const __attribute__((address_space(1))) void*)(g + r * 2048 + tid * 8),
        (__attribute__((address_space(3))) void*)(l + r * 2048 + tid * 8), 16, 0, 0);
}

#define WAITBAR(S)                                  \
  asm volatile(S ::: "memory");                     \
  __builtin_amdgcn_sched_barrier(0);                \
  __builtin_amdgcn_s_barrier();                     \
  __builtin_amdgcn_sched_barrier(0);

// B fragments register-direct from packed global (R10 pattern)
#define LOADB(BS, PB)                                                       \
  _Pragma("unroll")                                                         \
  for (int g = 0; g < 4; ++g)                                               \
    BS[g] = *reinterpret_cast<const short8*>((PB) + g * 512 + lane * 8);

// one K-tile: A-frags from LDS (8 ds_read_b128), B from regs (BS),
// B(t+1) VMEM loads + A(t+2) staging interleaved. Relaxed interior.
#define KTILE_BODY(BS_CUR, BS_NXT, PB_NXT, DO_B, DO_STAGE)                  \
  {                                                                         \
    short8 aF[4];                                                           \
    _Pragma("unroll")                                                       \
    for (int m4 = 0; m4 < 4; ++m4)                                          \
      aF[m4] = *reinterpret_cast<const short8*>(aC + m4 * 512);             \
    if (DO_B) { LOADB(BS_NXT, PB_NXT) }                                     \
    __builtin_amdgcn_s_setprio(1);                                          \
    _Pragma("unroll")                                                       \
    for (int m4 = 0; m4 < 4; ++m4)                                          \
      _Pragma("unroll")                                                     \
      for (int g = 0; g < 4; ++g)                                           \
        acc[m4][g] = __builtin_amdgcn_mfma_f32_16x16x32_bf16(               \
            aF[m4], BS_CUR[g], acc[m4][g], 0, 0, 0);                        \
    __builtin_amdgcn_s_setprio(0);                                          \
    _Pragma("unroll")                                                       \
    for (int m4 = 0; m4 < 4; ++m4)                                          \
      aF[m4] = *reinterpret_cast<const short8*>(aC + 2048 + m4 * 512);      \
    if (DO_STAGE) stageA(gAs, aN, tid);                                     \
    __builtin_amdgcn_s_setprio(1);                                          \
    _Pragma("unroll")                                                       \
    for (int m4 = 0; m4 < 4; ++m4)                                          \
      _Pragma("unroll")                                                     \
      for (int g = 0; g < 4; ++g)                                           \
        acc[4 + m4][g] = __builtin_amdgcn_mfma_f32_16x16x32_bf16(           \
            aF[m4], BS_CUR[g], acc[4 + m4][g], 0, 0, 0);                    \
    __builtin_amdgcn_s_setprio(0);                                          \
  }

// ---------------------------------------------------------------------------
// GEMM M=16384 Np=2048 K=1024. Tile 256x128, 4 waves (2wr x 2wc), wave =
// 128x64, acc[8][4] = 128 AGPR. PIPE-SPLIT OPERAND DELIVERY:
//   A-frags via LDS (ring-3 x 16KB = 48KB/block, global_load_lds staging,
//     depth-2 prefetch) -> LDS pipe ~1000 cyc/CU/tile
//   B-frags register-direct from L2-hot packed global (dbuf, unroll-2)
//     -> VMEM pipe ~1000-2000 cyc/CU/tile
// vs R6..R11 where ALL ~96KB went through ONE pipe (~1700+ serial).
// 2 blocks/CU (96KB LDS), 1 barrier/tile, steady vmcnt(8)
// (= B(t+1) 4 + A-stage(t+2) 4 in flight; A(t+1) guaranteed landed).
// ---------------------------------------------------------------------------
__global__ __launch_bounds__(256, 2) void lstm_gemm_kernel(
    const unsigned short* __restrict__ Ap,
    const unsigned short* __restrict__ Bp,
    const float* __restrict__ z,
    const float* __restrict__ b_i, const float* __restrict__ b_f,
    const float* __restrict__ b_c, const float* __restrict__ b_o,
    float* __restrict__ out) {
  __shared__ unsigned short lds[24576];  // 48KB = 3 slots x A-tile 16KB

  int tid  = threadIdx.x;
  int bid  = blockIdx.x;
  int sw   = (bid & 7) * 128 + (bid >> 3);  // 1024 % 8 == 0 -> bijective
  int bn   = sw & 15;    // 16 N-tiles (32 h * 4 gates)
  int bm   = sw >> 4;    // 64 M-tiles (256 rows)
  int lane = tid & 63;
  int wid  = tid >> 6;   // 0..3
  int wr   = wid >> 1;   // 0..1 -> 128 rows
  int wc   = wid & 1;    // 0..1 -> 16 h * 4 gates

  floatx4 acc[8][4];
#pragma unroll
  for (int m = 0; m < 8; ++m)
#pragma unroll
    for (int g = 0; g < 4; ++g)
      acc[m][g] = (floatx4){0.f, 0.f, 0.f, 0.f};

  const unsigned short* gA = Ap + (uint64_t)bm * (32 * 8192);
  const unsigned short* pB = Bp + (uint64_t)bn * (32 * 4096) + wc * 2048;

  short8 b0[4], b1[4];

  // prologue: B(t0) -> b0; stage A(t0) slot0, A(t1) slot1.
  LOADB(b0, pB)
  stageA(gA, lds, tid);
  stageA(gA + 8192, lds + 8192, tid);
  // loads complete in order: vmcnt(4) => B(t0) + A(t0) done, A(t1) in flight
  asm volatile("s_waitcnt vmcnt(4)" ::: "memory");
  __builtin_amdgcn_sched_barrier(0);
  __builtin_amdgcn_s_barrier();
  __builtin_amdgcn_sched_barrier(0);

  int cur = 0;
#pragma unroll 1
  for (int kt = 0; kt < 30; kt += 2) {
    // ---- tile kt (B in b0): load B(kt+1)->b1, stage A(kt+2)
    {
      int nxt2 = (cur >= 1) ? cur - 1 : 2;
      const unsigned short* aC = lds + cur * 8192 + wr * 4096 + lane * 8;
      unsigned short* aN = lds + nxt2 * 8192;
      const unsigned short* gAs = gA + (kt + 2) * 8192;
      KTILE_BODY(b0, b1, pB + (kt + 1) * 4096, true, true)
      WAITBAR("s_waitcnt vmcnt(8)")
      cur = (cur == 2) ? 0 : cur + 1;
    }
    // ---- tile kt+1 (B in b1): load B(kt+2)->b0, stage A(kt+3)
    {
      int nxt2 = (cur >= 1) ? cur - 1 : 2;
      const unsigned short* aC = lds + cur * 8192 + wr * 4096 + lane * 8;
      unsigned short* aN = lds + nxt2 * 8192;
      const unsigned short* gAs = gA + (kt + 3) * 8192;
      KTILE_BODY(b1, b0, pB + (kt + 2) * 4096, true, true)
      WAITBAR("s_waitcnt vmcnt(8)")
      cur = (cur == 2) ? 0 : cur + 1;
    }
  }

  // tile 30 (b0): load B(31)->b1, no A-stage; A(31) landed after vmcnt(4)
  {
    const unsigned short* aC = lds + cur * 8192 + wr * 4096 + lane * 8;
    unsigned short* aN = nullptr;
    const unsigned short* gAs = nullptr;
    KTILE_BODY(b0, b1, pB + 31 * 4096, true, false)
    WAITBAR("s_waitcnt vmcnt(4)")
    cur = (cur == 2) ? 0 : cur + 1;
  }
  // tile 31 (b1): nothing to load
  {
    const unsigned short* aC = lds + cur * 8192 + wr * 4096 + lane * 8;
    unsigned short* aN = nullptr;
    const unsigned short* gAs = nullptr;
    KTILE_BODY(b1, b0, pB, false, false)
  }

  // ---- fused LSTM epilogue (lane-local: acc frag index g == gate)
  int h = bn * 32 + wc * 16 + (lane & 15);
  float vbi = b_i[h], vbf = b_f[h], vbc = b_c[h], vbo = b_o[h];
  int rbase = bm * 256 + wr * 128 + ((lane >> 4) << 2);
  float* outH = out;
  float* outC = out + (uint64_t)B_DIM * H_DIM;
#pragma unroll
  for (int m = 0; m < 8; ++m) {
#pragma unroll
    for (int j = 0; j < 4; ++j) {
      int r = rbase + m * 16 + j;
      float pi = acc[m][0][j] + vbi;
      float pf = acc[m][1][j] + vbf;
      float pc = acc[m][2][j] + vbc;
      float po = acc[m][3][j] + vbo;
      float gi = 1.f / (1.f + __expf(-pi));
      float gf = 1.f / (1.f + __expf(-pf));
      float gc = 1.f - 2.f / (__expf(2.f * pc) + 1.f);  // tanh
      float go = 1.f / (1.f + __expf(-po));
      float zv = z[(uint64_t)r * H_DIM + h];
      float cn = gf * zv + gi * gc;
      float hn = go * (1.f - 2.f / (__expf(2.f * cn) + 1.f));
      outH[(uint64_t)r * H_DIM + h] = hn;
      outC[(uint64_t)r * H_DIM + h] = cn;
    }
  }
}

extern "C" void kernel_launch(void* const* d_in, const int* in_sizes, int n_in,
                              void* d_out, int out_size, void* d_ws, size_t ws_size,
                              hipStream_t stream) {
  const float* z  = (const float*)d_in[0];
  const float* x  = (const float*)d_in[1];
  const float* Wi = (const float*)d_in[2];
  const float* Wf = (const float*)d_in[3];
  const float* Wc = (const float*)d_in[4];
  const float* Wo = (const float*)d_in[5];
  const float* bi = (const float*)d_in[6];
  const float* bf = (const float*)d_in[7];
  const float* bc = (const float*)d_in[8];
  const float* bo = (const float*)d_in[9];
  const float* Ui = (const float*)d_in[10];
  const float* Uf = (const float*)d_in[11];
  const float* Uc = (const float*)d_in[12];
  const float* Uo = (const float*)d_in[13];

  unsigned short* Ap = (unsigned short*)d_ws;                          // 32 MB
  unsigned short* Bp = (unsigned short*)((char*)d_ws
                        + (size_t)B_DIM * KTOT * sizeof(unsigned short)); // +4 MB
  float* out = (float*)d_out;

  hipLaunchKernelGGL(pack_w_kernel, dim3((size_t)NP * KTOT / 8 / 256), dim3(256), 0, stream,
                     Wi, Wf, Wc, Wo, Ui, Uf, Uc, Uo, Bp);
  hipLaunchKernelGGL(pack_a_kernel, dim3((size_t)B_DIM * KTOT / 8 / 256), dim3(256), 0, stream,
                     x, z, Ap);
  hipLaunchKernelGGL(lstm_gemm_kernel, dim3(1024), dim3(256), 0, stream,
                     Ap, Bp, z, bi, bf, bc, bo, out);
}